// Round 17
// baseline (315.227 us; speedup 1.0000x reference)
//
#include <hip/hip_runtime.h>
#include <hip/hip_bf16.h>
#include <hip/hip_fp16.h>

typedef _Float16 half8 __attribute__((ext_vector_type(8)));
typedef _Float16 half4v __attribute__((ext_vector_type(4)));
typedef float f4 __attribute__((ext_vector_type(4)));
typedef float f16v __attribute__((ext_vector_type(16)));
typedef short short8 __attribute__((ext_vector_type(8)));
typedef unsigned short us8 __attribute__((ext_vector_type(8)));
typedef int i4 __attribute__((ext_vector_type(4)));

#define P_SZ 4096
#define CH 256      // hidden (qk) channels
#define CIN 512     // input channels
#define CV 512      // value channels
#define KVB 32      // keys per tile
#define L2E 1.4426950408889634f

__device__ __forceinline__ unsigned short f2bf(float f) {
  unsigned u = __float_as_uint(f);
  unsigned r = u + 0x7fffu + ((u >> 16) & 1u);
  return (unsigned short)(r >> 16);
}
__device__ __forceinline__ float bf2f(unsigned short h) {
  return __uint_as_float(((unsigned)h) << 16);
}

__device__ __forceinline__ void gload16(const void* g, void* l) {
  __builtin_amdgcn_global_load_lds(
      (const __attribute__((address_space(1))) unsigned int*)g,
      (__attribute__((address_space(3))) unsigned int*)l, 16, 0, 0);
}

// ---------------- W convert: fp16, Q side pre-scaled by log2(e) --------
__global__ __launch_bounds__(256) void wconv_kernel(
    const float* __restrict__ Wq, const float* __restrict__ Wk,
    _Float16* __restrict__ Wf) {
  const int i = blockIdx.x * 256 + threadIdx.x;   // 0..262143
  const int which = i >> 17;
  const int j = i & 131071;
  const float w = which ? Wk[j] : Wq[j] * L2E;
  Wf[i] = (_Float16)w;
}

// ---------------- Projection (fp16 inputs, fp32 MFMA accumulate), fp16 out --------
// LDS-staged X (coalesced f4 loads). Q: natural [b][p][256] (log2e-scaled).
// K: chunk-major tiles [b][tile32][o>>3][32key][8ch], key rows PERMUTED by
// kk -> swap(bits2,3)(kk) so attn's P fragments need no cross-half shuffle.
// FUSED V-emission (which==1): staged Xs tile -> fp16 Vt directly.
__global__ __launch_bounds__(512) void proj_kernel(
    const float* __restrict__ Xq, const float* __restrict__ bq,
    const float* __restrict__ Xk, const float* __restrict__ bk,
    const _Float16* __restrict__ Wf,
    _Float16* __restrict__ Qout, _Float16* __restrict__ Kout,
    _Float16* __restrict__ Vout) {
  __shared__ float Xs[64][65];             // [p_local][c_local], +1 pad
  const int which = blockIdx.z;
  const float* __restrict__ X = which ? Xk : Xq;
  const float* __restrict__ bias = which ? bk : bq;
  _Float16* __restrict__ out = which ? Kout : Qout;
  const float bscale = which ? 1.f : L2E;

  const int b = blockIdx.y;
  const int p0 = blockIdx.x * 64;
  const int tid = threadIdx.x;
  const int w = tid >> 6, l = tid & 63;
  const int wp = w >> 2, wo = w & 3;
  const int lr = l & 15, lg = l >> 4;

  const float* __restrict__ Xb = X + (size_t)b * CIN * P_SZ;
  const _Float16* __restrict__ Wfb = Wf + (size_t)which * 131072;

  f4 acc[2][4];
  #pragma unroll
  for (int m = 0; m < 2; ++m)
    #pragma unroll
    for (int n = 0; n < 4; ++n) acc[m][n] = (f4){0.f, 0.f, 0.f, 0.f};

  const int crow = tid >> 4;               // staging: c-row 0..31 (+32)
  const int pq4 = (tid & 15) * 4;          // staging: p-quad

  #pragma unroll 1
  for (int kc64 = 0; kc64 < CIN; kc64 += 64) {
    __syncthreads();                       // prior tile's reads complete
    #pragma unroll
    for (int h2 = 0; h2 < 2; ++h2) {
      const int c = crow + h2 * 32;
      const f4 x = *(const f4*)(Xb + (size_t)(kc64 + c) * P_SZ + p0 + pq4);
      Xs[pq4 + 0][c] = x[0];
      Xs[pq4 + 1][c] = x[1];
      Xs[pq4 + 2][c] = x[2];
      Xs[pq4 + 3][c] = x[3];
    }
    __syncthreads();

    // ---- fused V emission from the staged tile (K-side blocks only) ----
    if (which == 1) {
      half8 v;
      #pragma unroll
      for (int j = 0; j < 8; ++j) v[j] = (_Float16)Xs[w * 8 + j][l];
      _Float16* vd = Vout + (size_t)b * 2097152 + (size_t)(p0 >> 5) * 16384
                   + (size_t)(w >> 2) * 16384 + (w & 3) * 4096 + (kc64 + l) * 8;
      *(half8*)vd = v;
    }

    #pragma unroll
    for (int s = 0; s < 2; ++s) {
      const int kc = kc64 + s * 32;
      half8 ah[2];
      #pragma unroll
      for (int m = 0; m < 2; ++m) {
        const int pl = wp * 32 + m * 16 + lr;
        #pragma unroll
        for (int i = 0; i < 8; ++i)
          ah[m][i] = (_Float16)Xs[pl][s * 32 + lg * 8 + i];
      }
      half8 bh[4];
      #pragma unroll
      for (int n = 0; n < 4; ++n) {
        const size_t wi = (size_t)(wo * 64 + n * 16 + lr) * CIN + kc + lg * 8;
        bh[n] = *(const half8*)(Wfb + wi);
      }
      #pragma unroll
      for (int m = 0; m < 2; ++m)
        #pragma unroll
        for (int n = 0; n < 4; ++n)
          acc[m][n] = __builtin_amdgcn_mfma_f32_16x16x32_f16(ah[m], bh[n], acc[m][n], 0, 0, 0);
    }
  }

  #pragma unroll
  for (int n = 0; n < 4; ++n) {
    const int o = wo * 64 + n * 16 + lr;
    const float bv = bias[o] * bscale;
    #pragma unroll
    for (int m = 0; m < 2; ++m) {
      #pragma unroll
      for (int j = 0; j < 4; ++j) {
        const int p = p0 + wp * 32 + m * 16 + lg * 4 + j;
        const _Float16 val = (_Float16)(acc[m][n][j] + bv);
        if (which == 0) {
          out[((size_t)b * P_SZ + p) * CH + o] = val;
        } else {
          const int kk = p & 31;
          const int kswz = (kk & 19) | ((kk & 4) << 1) | ((kk & 8) >> 1);
          out[(size_t)b * 1048576 + (size_t)(p >> 5) * 8192
              + (size_t)(o >> 3) * 256 + kswz * 8 + (o & 7)] = val;
        }
      }
    }
  }
}

// ---------------- Fused flash attention (+ optional fused cross-segment merge) ----
// MODE 0: write Opart/Mp/Lp (external combine). MODE 1: direct write (NSEG==1).
// MODE 2: Opart/Mp/Lp + device-scope flag; LAST arriver of each (b,qt) unit merges
// both segments (fixed seg order -> bit-deterministic), LDS-transposes, writes out.
template <int NSEG, int MODE>
__global__ __launch_bounds__(512, 2) void attn_kernel(
    const _Float16* __restrict__ Qg, const _Float16* __restrict__ Kt,
    const _Float16* __restrict__ Vt, unsigned short* __restrict__ Opart,
    float* __restrict__ Mp, float* __restrict__ Lp, float* __restrict__ Og,
    int* __restrict__ flags) {
  __shared__ char K_l[3][16384];
  __shared__ char V_l[3][32768];
  __shared__ int is_last_sh;

  constexpr int nt = (P_SZ / NSEG) / KVB;
  int b, qt, seg;
  if (NSEG == 2) {
    const int g = blockIdx.x & 7;          // 8 (b,seg) groups -> 8 XCDs
    b = g >> 1; seg = g & 1; qt = blockIdx.x >> 3;
  } else {
    b = blockIdx.x & 3; seg = 0; qt = blockIdx.x >> 2;
  }

  const int tid = threadIdx.x;
  const int w = tid >> 6, l = tid & 63;
  const int hi = l >> 5, l31 = l & 31;
  const int wq = w >> 1, half = w & 1;

  const char* Kb = (const char*)Kt + (size_t)b * 2097152 + (size_t)seg * nt * 16384;
  const char* Vb = (const char*)Vt + (size_t)b * 4194304 + (size_t)seg * nt * 32768;

#define STAGE(BUF, T) do { \
    const char* ksrc = Kb + (size_t)(T) * 16384; \
    const char* vsrc = Vb + (size_t)(T) * 32768; \
    gload16(ksrc + tid * 16,         &K_l[BUF][w * 1024]); \
    gload16(ksrc + 8192 + tid * 16,  &K_l[BUF][8192 + w * 1024]); \
    gload16(vsrc + tid * 16,         &V_l[BUF][w * 1024]); \
    gload16(vsrc + 8192 + tid * 16,  &V_l[BUF][8192 + w * 1024]); \
    gload16(vsrc + 16384 + tid * 16, &V_l[BUF][16384 + w * 1024]); \
    gload16(vsrc + 24576 + tid * 16, &V_l[BUF][24576 + w * 1024]); \
  } while (0)

  // Q fragments: B-operand [q=lane&31][ch chunks], natural global layout
  half8 qf[16];
  {
    const char* qrow = (const char*)Qg +
        ((size_t)b * P_SZ + qt * 128 + wq * 32 + l31) * 512;
    #pragma unroll
    for (int m = 0; m < 16; ++m) qf[m] = *(const half8*)(qrow + m * 32 + hi * 16);
  }

  f16v acc[8];
  #pragma unroll
  for (int n = 0; n < 8; ++n)
    acc[n] = (f16v){0,0,0,0, 0,0,0,0, 0,0,0,0, 0,0,0,0};

  float m_run = -1e30f, lsum = 0.f;
  const int kread = hi * 512 + l31 * 16;                  // + m*1024
  const int vread = hi * 8192 + half * 4096 + l31 * 16;   // + n*512 (+16384 kh23)

  STAGE(0, 0); STAGE(1, 1);
  asm volatile("s_waitcnt vmcnt(6)" ::: "memory");
  asm volatile("s_barrier" ::: "memory");

  int bufc = 0;
  #pragma unroll 1
  for (int t = 0; t < nt; ++t) {
    // ---- swapped QK^T: S^T[key-row][q], duplicated across the ch-half pair ----
    const char* kb = &K_l[bufc][0] + kread;
    f16v s = (f16v){0,0,0,0, 0,0,0,0, 0,0,0,0, 0,0,0,0};
    __builtin_amdgcn_s_setprio(1);
    #pragma unroll
    for (int m = 0; m < 16; ++m) {
      half8 kf = *(const half8*)(kb + m * 1024);
      s = __builtin_amdgcn_mfma_f32_32x32x16_f16(kf, qf[m], s, 0, 0, 0);
    }
    __builtin_amdgcn_s_setprio(0);

    // ---- in-register online softmax over 32 keys (per q=l31), log2 domain ----
    float x0 = fmaxf(s[0], s[8]),  x1 = fmaxf(s[1], s[9]);
    float x2 = fmaxf(s[2], s[10]), x3 = fmaxf(s[3], s[11]);
    float x4 = fmaxf(s[4], s[12]), x5 = fmaxf(s[5], s[13]);
    float x6 = fmaxf(s[6], s[14]), x7 = fmaxf(s[7], s[15]);
    x0 = fmaxf(x0, x4); x1 = fmaxf(x1, x5); x2 = fmaxf(x2, x6); x3 = fmaxf(x3, x7);
    float pm = fmaxf(fmaxf(x0, x1), fmaxf(x2, x3));
    pm = fmaxf(pm, __shfl_xor(pm, 32));
    if (__any(pm > m_run + 12.f)) {          // rare rescale (defer-max, T13)
      const float mnew = fmaxf(m_run, pm);
      const float al = __builtin_amdgcn_exp2f(m_run - mnew);
      const int alb = __float_as_int(al);
      #pragma unroll
      for (int r = 0; r < 16; ++r) {
        const int cr = (r & 3) + 8 * (r >> 2);
        const float ar = __int_as_float(
            __builtin_amdgcn_ds_bpermute(cr * 4 + hi * 16, alb));
        #pragma unroll
        for (int n = 0; n < 8; ++n) acc[n][r] *= ar;
      }
      lsum *= al;
      m_run = mnew;
    }
    float p[16], psum;
    #pragma unroll
    for (int r = 0; r < 16; ++r) p[r] = __builtin_amdgcn_exp2f(s[r] - m_run);
    {
      float a0 = (p[0] + p[1]) + (p[2] + p[3]);
      float a1 = (p[4] + p[5]) + (p[6] + p[7]);
      float a2 = (p[8] + p[9]) + (p[10] + p[11]);
      float a3 = (p[12] + p[13]) + (p[14] + p[15]);
      psum = (a0 + a1) + (a2 + a3);
      psum += __shfl_xor(psum, 32);
    }
    lsum += psum;

    // ---- P -> fp16 A-fragments: direct pack (K rows pre-permuted in proj) ----
    i4 w0v, w1v;
    w0v[0] = __builtin_bit_cast(int, __builtin_amdgcn_cvt_pkrtz(p[0], p[1]));
    w0v[1] = __builtin_bit_cast(int, __builtin_amdgcn_cvt_pkrtz(p[2], p[3]));
    w0v[2] = __builtin_bit_cast(int, __builtin_amdgcn_cvt_pkrtz(p[4], p[5]));
    w0v[3] = __builtin_bit_cast(int, __builtin_amdgcn_cvt_pkrtz(p[6], p[7]));
    w1v[0] = __builtin_bit_cast(int, __builtin_amdgcn_cvt_pkrtz(p[8], p[9]));
    w1v[1] = __builtin_bit_cast(int, __builtin_amdgcn_cvt_pkrtz(p[10], p[11]));
    w1v[2] = __builtin_bit_cast(int, __builtin_amdgcn_cvt_pkrtz(p[12], p[13]));
    w1v[3] = __builtin_bit_cast(int, __builtin_amdgcn_cvt_pkrtz(p[14], p[15]));
    const half8 pa0 = __builtin_bit_cast(half8, w0v);
    const half8 pa1 = __builtin_bit_cast(half8, w1v);

    // ---- issue stage t+2 (2-deep pipeline) ----
    const int bufs = bufc == 0 ? 2 : bufc - 1;   // (bufc+2)%3
    if (t + 2 < nt) STAGE(bufs, t + 2);

    // ---- PV: acc[q][ch-half] += P * V ----
    const char* vb = &V_l[bufc][0] + vread;
    __builtin_amdgcn_s_setprio(1);
    #pragma unroll
    for (int n = 0; n < 8; ++n) {
      half8 v0 = *(const half8*)(vb + n * 512);
      acc[n] = __builtin_amdgcn_mfma_f32_32x32x16_f16(pa0, v0, acc[n], 0, 0, 0);
      half8 v1 = *(const half8*)(vb + 16384 + n * 512);
      acc[n] = __builtin_amdgcn_mfma_f32_32x32x16_f16(pa1, v1, acc[n], 0, 0, 0);
    }
    __builtin_amdgcn_s_setprio(0);

    if (t + 2 < nt) { asm volatile("s_waitcnt vmcnt(6)" ::: "memory"); }
    else            { asm volatile("s_waitcnt vmcnt(0)" ::: "memory"); }
    asm volatile("s_barrier" ::: "memory");
    bufc = bufc == 2 ? 0 : bufc + 1;
  }
#undef STAGE

  const int qg0 = qt * 128 + wq * 32;
  if (MODE != 1) {
    unsigned short* Ob = Opart +
        (((size_t)seg * 4 + b) * P_SZ + qg0) * 512 + half * 256 + l31;
    #pragma unroll
    for (int n = 0; n < 8; ++n) {
      #pragma unroll
      for (int r = 0; r < 16; ++r) {
        const int q = (r & 3) + 8 * (r >> 2) + 4 * hi;
        Ob[(size_t)q * 512 + n * 32] = f2bf(acc[n][r]);
      }
    }
    if (half == 0 && l < 32) {
      const size_t mi = ((size_t)seg * 4 + b) * P_SZ + qg0 + l31;
      Mp[mi] = m_run; Lp[mi] = lsum;
    }
    if (MODE == 2) {
      __threadfence();                           // release: Opart/Mp/Lp visible
      if (tid == 0) is_last_sh = atomicAdd(&flags[b * 32 + qt], 1);
      __syncthreads();
      if (is_last_sh == 1) {                     // last arriver merges the unit
        __threadfence();                         // acquire: peer's data visible
        float* Tb = (float*)(&K_l[0][0]) + (tid >> 8) * (64 * 65);
        const int t2 = tid & 255;
        #pragma unroll 1
        for (int rnd = 0; rnd < 8; ++rnd) {
          const int t16 = rnd * 2 + (tid >> 8);  // tile 0..15 = qh*8 + ct
          const int qh = t16 >> 3, ct = t16 & 7;
          const int q64 = qt * 128 + qh * 64;
          {
            const int qi = t2 >> 2, cj = t2 & 3;
            const int q = q64 + qi;
            const size_t i0 = (size_t)b * P_SZ + q;
            const size_t i1 = (size_t)(4 + b) * P_SZ + q;
            const float M = fmaxf(Mp[i0], Mp[i1]);
            float L = 0.f;
            float o[16];
            #pragma unroll
            for (int e = 0; e < 16; ++e) o[e] = 0.f;
            #pragma unroll
            for (int sdx = 0; sdx < 2; ++sdx) {  // FIXED order -> deterministic
              const size_t mi = sdx ? i1 : i0;
              const float wgt = __builtin_amdgcn_exp2f(Mp[mi] - M);
              L += wgt * Lp[mi];
              const unsigned short* src = Opart +
                  (((size_t)sdx * 4 + b) * P_SZ + q) * 512 + ct * 64 + cj * 16;
              const us8 ua = ((const us8*)src)[0];
              const us8 ub = ((const us8*)src)[1];
              #pragma unroll
              for (int e = 0; e < 8; ++e) {
                o[e]     += wgt * bf2f(ua[e]);
                o[8 + e] += wgt * bf2f(ub[e]);
              }
            }
            const float inv = 1.f / L;
            #pragma unroll
            for (int e = 0; e < 16; ++e) Tb[qi * 65 + cj * 16 + e] = o[e] * inv;
          }
          __syncthreads();
          {
            const int ci = t2 >> 2, qj = t2 & 3;
            #pragma unroll
            for (int i = 0; i < 4; ++i) {
              f4 v;
              #pragma unroll
              for (int e = 0; e < 4; ++e) v[e] = Tb[(qj * 16 + i * 4 + e) * 65 + ci];
              *(f4*)&Og[((size_t)b * CV + ct * 64 + ci) * P_SZ + q64 + qj * 16 + i * 4] = v;
            }
          }
          __syncthreads();
        }
      }
    }
  } else {
    float linv[16];
    const int lb = __float_as_int(lsum);
    #pragma unroll
    for (int r = 0; r < 16; ++r) {
      const int cr = (r & 3) + 8 * (r >> 2);
      const float lq = __int_as_float(__builtin_amdgcn_ds_bpermute(cr * 4 + hi * 16, lb));
      linv[r] = 1.f / lq;
    }
    #pragma unroll
    for (int n = 0; n < 8; ++n) {
      #pragma unroll
      for (int r = 0; r < 16; ++r) {
        const int q = (r & 3) + 8 * (r >> 2) + 4 * hi;
        Og[((size_t)b * CV + half * 256 + n * 32 + l31) * P_SZ + qg0 + q] =
            acc[n][r] * linv[r];
      }
    }
  }
}

// ---------------- Combine (fallback for NSEG==1 Opart path) ----------------
template <int NSEG>
__global__ __launch_bounds__(256) void combine_kernel(
    const unsigned short* __restrict__ Opart, const float* __restrict__ Mp,
    const float* __restrict__ Lp, float* __restrict__ Og) {
  __shared__ float T[64][65];
  const int bx = blockIdx.x;
  const int ct = bx & 7, qt = (bx >> 3) & 63, b = bx >> 9;
  const int tid = threadIdx.x;
  {
    const int qi = tid >> 2, cj = tid & 3;
    const int q = qt * 64 + qi;
    const size_t mibase = (size_t)b * P_SZ + q;
    float M = -1e30f;
    #pragma unroll
    for (int s = 0; s < NSEG; ++s) M = fmaxf(M, Mp[(size_t)s * 4 * P_SZ + mibase]);
    float L = 0.f;
    float o[16];
    #pragma unroll
    for (int e = 0; e < 16; ++e) o[e] = 0.f;
    #pragma unroll
    for (int s = 0; s < NSEG; ++s) {
      const float wgt = __builtin_amdgcn_exp2f(Mp[(size_t)s * 4 * P_SZ + mibase] - M);
      L += wgt * Lp[(size_t)s * 4 * P_SZ + mibase];
      const unsigned short* src = Opart +
          (((size_t)s * 4 + b) * P_SZ + q) * 512 + ct * 64 + cj * 16;
      const us8 ua = ((const us8*)src)[0];
      const us8 ub = ((const us8*)src)[1];
      #pragma unroll
      for (int e = 0; e < 8; ++e) {
        o[e]     += wgt * bf2f(ua[e]);
        o[8 + e] += wgt * bf2f(ub[e]);
      }
    }
    const float inv = 1.f / L;
    #pragma unroll
    for (int e = 0; e < 16; ++e) T[qi][cj * 16 + e] = o[e] * inv;
  }
  __syncthreads();
  const int ci = tid >> 2, qj = tid & 3;
  #pragma unroll
  for (int i = 0; i < 4; ++i) {
    f4 v;
    #pragma unroll
    for (int e = 0; e < 4; ++e) v[e] = T[qj * 16 + i * 4 + e][ci];
    *(f4*)&Og[((size_t)b * CV + ct * 64 + ci) * P_SZ + qt * 64 + qj * 16 + i * 4] = v;
  }
}

extern "C" void kernel_launch(void* const* d_in, const int* in_sizes, int n_in,
                              void* d_out, int out_size, void* d_ws, size_t ws_size,
                              hipStream_t stream) {
  const float* x  = (const float*)d_in[0];
  const float* f  = (const float*)d_in[1];
  const float* Wq = (const float*)d_in[2];
  const float* bq = (const float*)d_in[3];
  const float* Wk = (const float*)d_in[4];
  const float* bk = (const float*)d_in[5];
  float* out = (float*)d_out;

  char* ws = (char*)d_ws;
  _Float16* Qf = (_Float16*)ws;                                   // 8 MB
  _Float16* Kf = (_Float16*)(ws + ((size_t)8 << 20));             // 8 MB (key rows permuted)
  _Float16* Vf = (_Float16*)(ws + ((size_t)16 << 20));            // 16 MB
  float* Mp    = (float*)(ws + ((size_t)32 << 20));               // 128 KB
  float* Lp    = (float*)(ws + ((size_t)32 << 20) + (256 << 10)); // 128 KB
  _Float16* Wf = (_Float16*)(ws + ((size_t)32 << 20) + (512 << 10)); // 512 KB (fp16 W)
  int* flags   = (int*)(ws + ((size_t)33 << 20));                 // 512 B
  unsigned short* Opart = (unsigned short*)(ws + ((size_t)34 << 20)); // NSEG*16 MB bf16

  wconv_kernel<<<dim3(1024), dim3(256), 0, stream>>>(Wq, Wk, Wf);
  proj_kernel<<<dim3(64, 4, 2), dim3(512), 0, stream>>>(x, bq, f, bk, Wf, Qf, Kf, Vf);

  const size_t need2 = ((size_t)34 << 20) + ((size_t)32 << 20);
  const size_t need1 = ((size_t)34 << 20) + ((size_t)16 << 20);
  if (ws_size >= need2) {
    hipMemsetAsync(flags, 0, 128 * sizeof(int), stream);
    attn_kernel<2, 2><<<dim3(256), dim3(512), 0, stream>>>(Qf, Kf, Vf, Opart, Mp, Lp, out, flags);
  } else if (ws_size >= need1) {
    attn_kernel<1, 0><<<dim3(128), dim3(512), 0, stream>>>(Qf, Kf, Vf, Opart, Mp, Lp, nullptr, nullptr);
    combine_kernel<1><<<dim3(2048), dim3(256), 0, stream>>>(Opart, Mp, Lp, out);
  } else {
    attn_kernel<1, 1><<<dim3(128), dim3(512), 0, stream>>>(Qf, Kf, Vf, nullptr, nullptr, nullptr, out, nullptr);
  }
}

// Round 18
// 210.518 us; speedup vs baseline: 1.4974x; 1.4974x over previous
//
#include <hip/hip_runtime.h>
#include <hip/hip_bf16.h>
#include <hip/hip_fp16.h>

typedef _Float16 half8 __attribute__((ext_vector_type(8)));
typedef _Float16 half4v __attribute__((ext_vector_type(4)));
typedef float f4 __attribute__((ext_vector_type(4)));
typedef float f16v __attribute__((ext_vector_type(16)));
typedef short short8 __attribute__((ext_vector_type(8)));
typedef unsigned short us8 __attribute__((ext_vector_type(8)));
typedef int i4 __attribute__((ext_vector_type(4)));

#define P_SZ 4096
#define CH 256      // hidden (qk) channels
#define CIN 512     // input channels
#define CV 512      // value channels
#define KVB 32      // keys per tile
#define L2E 1.4426950408889634f

__device__ __forceinline__ unsigned short f2bf(float f) {
  unsigned u = __float_as_uint(f);
  unsigned r = u + 0x7fffu + ((u >> 16) & 1u);
  return (unsigned short)(r >> 16);
}
__device__ __forceinline__ float bf2f(unsigned short h) {
  return __uint_as_float(((unsigned)h) << 16);
}

__device__ __forceinline__ void gload16(const void* g, void* l) {
  __builtin_amdgcn_global_load_lds(
      (const __attribute__((address_space(1))) unsigned int*)g,
      (__attribute__((address_space(3))) unsigned int*)l, 16, 0, 0);
}

// ---------------- W convert: fp16, Q side pre-scaled by log2(e) --------
__global__ __launch_bounds__(256) void wconv_kernel(
    const float* __restrict__ Wq, const float* __restrict__ Wk,
    _Float16* __restrict__ Wf) {
  const int i = blockIdx.x * 256 + threadIdx.x;   // 0..262143
  const int which = i >> 17;
  const int j = i & 131071;
  const float w = which ? Wk[j] : Wq[j] * L2E;
  Wf[i] = (_Float16)w;
}

// ---------------- Projection (fp16 inputs, fp32 MFMA accumulate), fp16 out --------
// LDS-staged X (coalesced f4 loads). Q: natural [b][p][256] (log2e-scaled).
// K: chunk-major tiles [b][tile32][o>>3][32key][8ch], key rows PERMUTED by
// kk -> swap(bits2,3)(kk) so attn's P fragments need no cross-half shuffle.
// FUSED V-emission (which==1): staged Xs tile -> fp16 Vt directly.
__global__ __launch_bounds__(512) void proj_kernel(
    const float* __restrict__ Xq, const float* __restrict__ bq,
    const float* __restrict__ Xk, const float* __restrict__ bk,
    const _Float16* __restrict__ Wf,
    _Float16* __restrict__ Qout, _Float16* __restrict__ Kout,
    _Float16* __restrict__ Vout) {
  __shared__ float Xs[64][65];             // [p_local][c_local], +1 pad
  const int which = blockIdx.z;
  const float* __restrict__ X = which ? Xk : Xq;
  const float* __restrict__ bias = which ? bk : bq;
  _Float16* __restrict__ out = which ? Kout : Qout;
  const float bscale = which ? 1.f : L2E;

  const int b = blockIdx.y;
  const int p0 = blockIdx.x * 64;
  const int tid = threadIdx.x;
  const int w = tid >> 6, l = tid & 63;
  const int wp = w >> 2, wo = w & 3;
  const int lr = l & 15, lg = l >> 4;

  const float* __restrict__ Xb = X + (size_t)b * CIN * P_SZ;
  const _Float16* __restrict__ Wfb = Wf + (size_t)which * 131072;

  f4 acc[2][4];
  #pragma unroll
  for (int m = 0; m < 2; ++m)
    #pragma unroll
    for (int n = 0; n < 4; ++n) acc[m][n] = (f4){0.f, 0.f, 0.f, 0.f};

  const int crow = tid >> 4;               // staging: c-row 0..31 (+32)
  const int pq4 = (tid & 15) * 4;          // staging: p-quad

  #pragma unroll 1
  for (int kc64 = 0; kc64 < CIN; kc64 += 64) {
    __syncthreads();                       // prior tile's reads complete
    #pragma unroll
    for (int h2 = 0; h2 < 2; ++h2) {
      const int c = crow + h2 * 32;
      const f4 x = *(const f4*)(Xb + (size_t)(kc64 + c) * P_SZ + p0 + pq4);
      Xs[pq4 + 0][c] = x[0];
      Xs[pq4 + 1][c] = x[1];
      Xs[pq4 + 2][c] = x[2];
      Xs[pq4 + 3][c] = x[3];
    }
    __syncthreads();

    // ---- fused V emission from the staged tile (K-side blocks only) ----
    if (which == 1) {
      half8 v;
      #pragma unroll
      for (int j = 0; j < 8; ++j) v[j] = (_Float16)Xs[w * 8 + j][l];
      _Float16* vd = Vout + (size_t)b * 2097152 + (size_t)(p0 >> 5) * 16384
                   + (size_t)(w >> 2) * 16384 + (w & 3) * 4096 + (kc64 + l) * 8;
      *(half8*)vd = v;
    }

    #pragma unroll
    for (int s = 0; s < 2; ++s) {
      const int kc = kc64 + s * 32;
      half8 ah[2];
      #pragma unroll
      for (int m = 0; m < 2; ++m) {
        const int pl = wp * 32 + m * 16 + lr;
        #pragma unroll
        for (int i = 0; i < 8; ++i)
          ah[m][i] = (_Float16)Xs[pl][s * 32 + lg * 8 + i];
      }
      half8 bh[4];
      #pragma unroll
      for (int n = 0; n < 4; ++n) {
        const size_t wi = (size_t)(wo * 64 + n * 16 + lr) * CIN + kc + lg * 8;
        bh[n] = *(const half8*)(Wfb + wi);
      }
      #pragma unroll
      for (int m = 0; m < 2; ++m)
        #pragma unroll
        for (int n = 0; n < 4; ++n)
          acc[m][n] = __builtin_amdgcn_mfma_f32_16x16x32_f16(ah[m], bh[n], acc[m][n], 0, 0, 0);
    }
  }

  #pragma unroll
  for (int n = 0; n < 4; ++n) {
    const int o = wo * 64 + n * 16 + lr;
    const float bv = bias[o] * bscale;
    #pragma unroll
    for (int m = 0; m < 2; ++m) {
      #pragma unroll
      for (int j = 0; j < 4; ++j) {
        const int p = p0 + wp * 32 + m * 16 + lg * 4 + j;
        const _Float16 val = (_Float16)(acc[m][n][j] + bv);
        if (which == 0) {
          out[((size_t)b * P_SZ + p) * CH + o] = val;
        } else {
          const int kk = p & 31;
          const int kswz = (kk & 19) | ((kk & 4) << 1) | ((kk & 8) >> 1);
          out[(size_t)b * 1048576 + (size_t)(p >> 5) * 8192
              + (size_t)(o >> 3) * 256 + kswz * 8 + (o & 7)] = val;
        }
      }
    }
  }
}

// ---------------- Fused flash attention: swapped QK^T, in-register softmax ----------------
// (best-measured structure, frozen: KVB=32, 3-buffer 2-deep pipeline,
//  vmcnt(6) counted waits, 1 barrier/iter, defer-max THR=12, raw v_exp_f32.)
template <int NSEG, bool DIRECT>
__global__ __launch_bounds__(512, 2) void attn_kernel(
    const _Float16* __restrict__ Qg, const _Float16* __restrict__ Kt,
    const _Float16* __restrict__ Vt, unsigned short* __restrict__ Opart,
    float* __restrict__ Mp, float* __restrict__ Lp, float* __restrict__ Og) {
  __shared__ char K_l[3][16384];
  __shared__ char V_l[3][32768];

  constexpr int nt = (P_SZ / NSEG) / KVB;
  int b, qt, seg;
  if (NSEG == 2) {
    const int g = blockIdx.x & 7;          // 8 (b,seg) groups -> 8 XCDs
    b = g >> 1; seg = g & 1; qt = blockIdx.x >> 3;
  } else {
    b = blockIdx.x & 3; seg = 0; qt = blockIdx.x >> 2;
  }

  const int tid = threadIdx.x;
  const int w = tid >> 6, l = tid & 63;
  const int hi = l >> 5, l31 = l & 31;
  const int wq = w >> 1, half = w & 1;

  const char* Kb = (const char*)Kt + (size_t)b * 2097152 + (size_t)seg * nt * 16384;
  const char* Vb = (const char*)Vt + (size_t)b * 4194304 + (size_t)seg * nt * 32768;

#define STAGE(BUF, T) do { \
    const char* ksrc = Kb + (size_t)(T) * 16384; \
    const char* vsrc = Vb + (size_t)(T) * 32768; \
    gload16(ksrc + tid * 16,         &K_l[BUF][w * 1024]); \
    gload16(ksrc + 8192 + tid * 16,  &K_l[BUF][8192 + w * 1024]); \
    gload16(vsrc + tid * 16,         &V_l[BUF][w * 1024]); \
    gload16(vsrc + 8192 + tid * 16,  &V_l[BUF][8192 + w * 1024]); \
    gload16(vsrc + 16384 + tid * 16, &V_l[BUF][16384 + w * 1024]); \
    gload16(vsrc + 24576 + tid * 16, &V_l[BUF][24576 + w * 1024]); \
  } while (0)

  // Q fragments: B-operand [q=lane&31][ch chunks], natural global layout
  half8 qf[16];
  {
    const char* qrow = (const char*)Qg +
        ((size_t)b * P_SZ + qt * 128 + wq * 32 + l31) * 512;
    #pragma unroll
    for (int m = 0; m < 16; ++m) qf[m] = *(const half8*)(qrow + m * 32 + hi * 16);
  }

  f16v acc[8];
  #pragma unroll
  for (int n = 0; n < 8; ++n)
    acc[n] = (f16v){0,0,0,0, 0,0,0,0, 0,0,0,0, 0,0,0,0};

  float m_run = -1e30f, lsum = 0.f;
  const int kread = hi * 512 + l31 * 16;                  // + m*1024
  const int vread = hi * 8192 + half * 4096 + l31 * 16;   // + n*512 (+16384 kh23)

  STAGE(0, 0); STAGE(1, 1);
  asm volatile("s_waitcnt vmcnt(6)" ::: "memory");
  asm volatile("s_barrier" ::: "memory");

  int bufc = 0;
  #pragma unroll 1
  for (int t = 0; t < nt; ++t) {
    // ---- swapped QK^T: S^T[key-row][q], duplicated across the ch-half pair ----
    const char* kb = &K_l[bufc][0] + kread;
    f16v s = (f16v){0,0,0,0, 0,0,0,0, 0,0,0,0, 0,0,0,0};
    __builtin_amdgcn_s_setprio(1);
    #pragma unroll
    for (int m = 0; m < 16; ++m) {
      half8 kf = *(const half8*)(kb + m * 1024);
      s = __builtin_amdgcn_mfma_f32_32x32x16_f16(kf, qf[m], s, 0, 0, 0);
    }
    __builtin_amdgcn_s_setprio(0);

    // ---- in-register online softmax over 32 keys (per q=l31), log2 domain ----
    float x0 = fmaxf(s[0], s[8]),  x1 = fmaxf(s[1], s[9]);
    float x2 = fmaxf(s[2], s[10]), x3 = fmaxf(s[3], s[11]);
    float x4 = fmaxf(s[4], s[12]), x5 = fmaxf(s[5], s[13]);
    float x6 = fmaxf(s[6], s[14]), x7 = fmaxf(s[7], s[15]);
    x0 = fmaxf(x0, x4); x1 = fmaxf(x1, x5); x2 = fmaxf(x2, x6); x3 = fmaxf(x3, x7);
    float pm = fmaxf(fmaxf(x0, x1), fmaxf(x2, x3));
    pm = fmaxf(pm, __shfl_xor(pm, 32));
    if (__any(pm > m_run + 12.f)) {          // rare rescale (defer-max, T13)
      const float mnew = fmaxf(m_run, pm);
      const float al = __builtin_amdgcn_exp2f(m_run - mnew);
      const int alb = __float_as_int(al);
      #pragma unroll
      for (int r = 0; r < 16; ++r) {
        const int cr = (r & 3) + 8 * (r >> 2);
        const float ar = __int_as_float(
            __builtin_amdgcn_ds_bpermute(cr * 4 + hi * 16, alb));
        #pragma unroll
        for (int n = 0; n < 8; ++n) acc[n][r] *= ar;
      }
      lsum *= al;
      m_run = mnew;
    }
    float p[16], psum;
    #pragma unroll
    for (int r = 0; r < 16; ++r) p[r] = __builtin_amdgcn_exp2f(s[r] - m_run);
    {
      float a0 = (p[0] + p[1]) + (p[2] + p[3]);
      float a1 = (p[4] + p[5]) + (p[6] + p[7]);
      float a2 = (p[8] + p[9]) + (p[10] + p[11]);
      float a3 = (p[12] + p[13]) + (p[14] + p[15]);
      psum = (a0 + a1) + (a2 + a3);
      psum += __shfl_xor(psum, 32);
    }
    lsum += psum;

    // ---- P -> fp16 A-fragments: direct pack (K rows pre-permuted in proj) ----
    i4 w0v, w1v;
    w0v[0] = __builtin_bit_cast(int, __builtin_amdgcn_cvt_pkrtz(p[0], p[1]));
    w0v[1] = __builtin_bit_cast(int, __builtin_amdgcn_cvt_pkrtz(p[2], p[3]));
    w0v[2] = __builtin_bit_cast(int, __builtin_amdgcn_cvt_pkrtz(p[4], p[5]));
    w0v[3] = __builtin_bit_cast(int, __builtin_amdgcn_cvt_pkrtz(p[6], p[7]));
    w1v[0] = __builtin_bit_cast(int, __builtin_amdgcn_cvt_pkrtz(p[8], p[9]));
    w1v[1] = __builtin_bit_cast(int, __builtin_amdgcn_cvt_pkrtz(p[10], p[11]));
    w1v[2] = __builtin_bit_cast(int, __builtin_amdgcn_cvt_pkrtz(p[12], p[13]));
    w1v[3] = __builtin_bit_cast(int, __builtin_amdgcn_cvt_pkrtz(p[14], p[15]));
    const half8 pa0 = __builtin_bit_cast(half8, w0v);
    const half8 pa1 = __builtin_bit_cast(half8, w1v);

    // ---- issue stage t+2 (2-deep pipeline) ----
    const int bufs = bufc == 0 ? 2 : bufc - 1;   // (bufc+2)%3
    if (t + 2 < nt) STAGE(bufs, t + 2);

    // ---- PV: acc[q][ch-half] += P * V ----
    const char* vb = &V_l[bufc][0] + vread;
    __builtin_amdgcn_s_setprio(1);
    #pragma unroll
    for (int n = 0; n < 8; ++n) {
      half8 v0 = *(const half8*)(vb + n * 512);
      acc[n] = __builtin_amdgcn_mfma_f32_32x32x16_f16(pa0, v0, acc[n], 0, 0, 0);
      half8 v1 = *(const half8*)(vb + 16384 + n * 512);
      acc[n] = __builtin_amdgcn_mfma_f32_32x32x16_f16(pa1, v1, acc[n], 0, 0, 0);
    }
    __builtin_amdgcn_s_setprio(0);

    if (t + 2 < nt) { asm volatile("s_waitcnt vmcnt(6)" ::: "memory"); }
    else            { asm volatile("s_waitcnt vmcnt(0)" ::: "memory"); }
    asm volatile("s_barrier" ::: "memory");
    bufc = bufc == 2 ? 0 : bufc + 1;
  }
#undef STAGE

  const int qg0 = qt * 128 + wq * 32;
  if (!DIRECT) {
    unsigned short* Ob = Opart +
        (((size_t)seg * 4 + b) * P_SZ + qg0) * 512 + half * 256 + l31;
    #pragma unroll
    for (int n = 0; n < 8; ++n) {
      #pragma unroll
      for (int r = 0; r < 16; ++r) {
        const int q = (r & 3) + 8 * (r >> 2) + 4 * hi;
        Ob[(size_t)q * 512 + n * 32] = f2bf(acc[n][r]);
      }
    }
    if (half == 0 && l < 32) {
      const size_t mi = ((size_t)seg * 4 + b) * P_SZ + qg0 + l31;
      Mp[mi] = m_run; Lp[mi] = lsum;
    }
  } else {
    float linv[16];
    const int lb = __float_as_int(lsum);
    #pragma unroll
    for (int r = 0; r < 16; ++r) {
      const int cr = (r & 3) + 8 * (r >> 2);
      const float lq = __int_as_float(__builtin_amdgcn_ds_bpermute(cr * 4 + hi * 16, lb));
      linv[r] = 1.f / lq;
    }
    #pragma unroll
    for (int n = 0; n < 8; ++n) {
      #pragma unroll
      for (int r = 0; r < 16; ++r) {
        const int q = (r & 3) + 8 * (r >> 2) + 4 * hi;
        Og[((size_t)b * CV + half * 256 + n * 32 + l31) * P_SZ + qg0 + q] =
            acc[n][r] * linv[r];
      }
    }
  }
}

// ---------------- Combine: merge kv-segments, normalize, transpose [q][ch]->[ch][q] ----
template <int NSEG>
__global__ __launch_bounds__(256) void combine_kernel(
    const unsigned short* __restrict__ Opart, const float* __restrict__ Mp,
    const float* __restrict__ Lp, float* __restrict__ Og) {
  __shared__ float T[64][65];
  const int bx = blockIdx.x;
  const int ct = bx & 7, qt = (bx >> 3) & 63, b = bx >> 9;
  const int tid = threadIdx.x;
  {
    const int qi = tid >> 2, cj = tid & 3;
    const int q = qt * 64 + qi;
    const size_t mibase = (size_t)b * P_SZ + q;
    float M = -1e30f;
    #pragma unroll
    for (int s = 0; s < NSEG; ++s) M = fmaxf(M, Mp[(size_t)s * 4 * P_SZ + mibase]);
    float L = 0.f;
    float o[16];
    #pragma unroll
    for (int e = 0; e < 16; ++e) o[e] = 0.f;
    #pragma unroll
    for (int s = 0; s < NSEG; ++s) {
      const float wgt = __builtin_amdgcn_exp2f(Mp[(size_t)s * 4 * P_SZ + mibase] - M);
      L += wgt * Lp[(size_t)s * 4 * P_SZ + mibase];
      const unsigned short* src = Opart +
          (((size_t)s * 4 + b) * P_SZ + q) * 512 + ct * 64 + cj * 16;
      const us8 ua = ((const us8*)src)[0];
      const us8 ub = ((const us8*)src)[1];
      #pragma unroll
      for (int e = 0; e < 8; ++e) {
        o[e]     += wgt * bf2f(ua[e]);
        o[8 + e] += wgt * bf2f(ub[e]);
      }
    }
    const float inv = 1.f / L;
    #pragma unroll
    for (int e = 0; e < 16; ++e) T[qi][cj * 16 + e] = o[e] * inv;
  }
  __syncthreads();
  const int ci = tid >> 2, qj = tid & 3;
  #pragma unroll
  for (int i = 0; i < 4; ++i) {
    f4 v;
    #pragma unroll
    for (int e = 0; e < 4; ++e) v[e] = T[qj * 16 + i * 4 + e][ci];
    *(f4*)&Og[((size_t)b * CV + ct * 64 + ci) * P_SZ + qt * 64 + qj * 16 + i * 4] = v;
  }
}

extern "C" void kernel_launch(void* const* d_in, const int* in_sizes, int n_in,
                              void* d_out, int out_size, void* d_ws, size_t ws_size,
                              hipStream_t stream) {
  const float* x  = (const float*)d_in[0];
  const float* f  = (const float*)d_in[1];
  const float* Wq = (const float*)d_in[2];
  const float* bq = (const float*)d_in[3];
  const float* Wk = (const float*)d_in[4];
  const float* bk = (const float*)d_in[5];
  float* out = (float*)d_out;

  char* ws = (char*)d_ws;
  _Float16* Qf = (_Float16*)ws;                                   // 8 MB
  _Float16* Kf = (_Float16*)(ws + ((size_t)8 << 20));             // 8 MB (key rows permuted)
  _Float16* Vf = (_Float16*)(ws + ((size_t)16 << 20));            // 16 MB
  float* Mp    = (float*)(ws + ((size_t)32 << 20));               // 128 KB
  float* Lp    = (float*)(ws + ((size_t)32 << 20) + (256 << 10)); // 128 KB
  _Float16* Wf = (_Float16*)(ws + ((size_t)32 << 20) + (512 << 10)); // 512 KB (fp16 W)
  unsigned short* Opart = (unsigned short*)(ws + ((size_t)34 << 20)); // NSEG*16 MB bf16

  wconv_kernel<<<dim3(1024), dim3(256), 0, stream>>>(Wq, Wk, Wf);
  proj_kernel<<<dim3(64, 4, 2), dim3(512), 0, stream>>>(x, bq, f, bk, Wf, Qf, Kf, Vf);

  const size_t need2 = ((size_t)34 << 20) + ((size_t)32 << 20);
  const size_t need1 = ((size_t)34 << 20) + ((size_t)16 << 20);
  if (ws_size >= need2) {
    attn_kernel<2, false><<<dim3(256), dim3(512), 0, stream>>>(Qf, Kf, Vf, Opart, Mp, Lp, nullptr);
    combine_kernel<2><<<dim3(2048), dim3(256), 0, stream>>>(Opart, Mp, Lp, out);
  } else if (ws_size >= need1) {
    attn_kernel<1, false><<<dim3(128), dim3(512), 0, stream>>>(Qf, Kf, Vf, Opart, Mp, Lp, nullptr);
    combine_kernel<1><<<dim3(2048), dim3(256), 0, stream>>>(Opart, Mp, Lp, out);
  } else {
    attn_kernel<1, true><<<dim3(128), dim3(512), 0, stream>>>(Qf, Kf, Vf, nullptr, nullptr, nullptr, out);
  }
}